// Round 4
// baseline (117.223 us; speedup 1.0000x reference)
//
#include <hip/hip_runtime.h>
#include <hip/hip_bf16.h>

// DecorrelationGradient, KAPPA = 0.5:
//   out = 0.5 * (X^T X / N) - 0.5   (diag terms cancel exactly at k=0.5)
// X [16384, 768] fp32.
//
// R4: harness ws-poison fill (41us @ 268MB) is a fixed tax inside the loop;
//     controllable budget was transpose~35 + gemm~20 + reduce~12.
//     - transpose: was 16 scalar ds_read_u16/thread -> rewrite with dword-packed
//       transposed LDS tile (stride 33 dwords, <=2-way banks everywhere)
//     - reduce: vectorize x8 (uint4 of bf16), drop the strided mirror scatter
//     - mirror: separate kernel, LDS-transposed, coalesced both sides
// K1: transpose+cast X -> XT [768,16384] bf16 in d_ws
// K2: MFMA GEMM, upper tile-pairs, 128x128, BK=32, KSPLIT=32, bf16 partials
// K3: reduce 32 partials -> affine -> write upper tiles (coalesced)
// K4: mirror 15 off-diag tiles transposed

#define D_DIM    768
#define K_DIM    16384
#define NPAIR    21
#define KSPLIT   32
#define XT_BYTES   ((size_t)D_DIM * K_DIM * 2)                // 24 MiB
#define PART_BYTES ((size_t)KSPLIT * NPAIR * 16384 * 2)       // 21 MiB

__device__ __constant__ int MI_TAB[NPAIR] = {0,0,0,0,0,0, 1,1,1,1,1, 2,2,2,2, 3,3,3, 4,4, 5};
__device__ __constant__ int NI_TAB[NPAIR] = {0,1,2,3,4,5, 1,2,3,4,5, 2,3,4,5, 3,4,5, 4,5, 5};
// off-diagonal pairs (mi<ni): 15
__device__ __constant__ int MI_OD[15] = {0,0,0,0,0, 1,1,1,1, 2,2,2, 3,3, 4};
__device__ __constant__ int NI_OD[15] = {1,2,3,4,5, 2,3,4,5, 3,4,5, 4,5, 5};

typedef __attribute__((ext_vector_type(8))) short short8;     // bf16 A/B frag
typedef __attribute__((ext_vector_type(4))) float floatx4;    // fp32 C/D frag

typedef __attribute__((address_space(3))) unsigned short lds_ushort;
typedef __attribute__((address_space(1))) const unsigned short g_ushort;

__device__ __forceinline__ void load_lds16(const unsigned short* g, unsigned short* l) {
  __builtin_amdgcn_global_load_lds((g_ushort*)g, (lds_ushort*)l, 16, 0, 0);
}

__device__ __forceinline__ unsigned int f2bf_u(float f) {     // RNE, as uint
  unsigned int u = __float_as_uint(f);
  u += 0x7fffu + ((u >> 16) & 1u);
  return u >> 16;
}

// ---------------- K1: transpose + cast -------------------------------------
// 64n x 64d tiles. Each thread casts two n-adjacent float4s and packs them
// column-wise into dwords (low short = even n), scattering 4 ds_write_b32
// into tileT[d][n/2]. Row stride 33 dwords (odd) => every phase <=2-way bank
// aliasing (free, m136). Phase 2: 4 dword reads -> 16B coalesced store.
__global__ __launch_bounds__(256) void transpose_cast_kernel(
    const float* __restrict__ x, unsigned short* __restrict__ xt) {
  __shared__ __align__(16) unsigned int tileT[64 * 33];   // [d][npair], 8.25 KiB
  const int d0 = blockIdx.x * 64;    // 12 over d
  const int n0 = blockIdx.y * 64;    // 256 over n
  const int t  = threadIdx.x;
  const int f4 = t & 15;             // d float4 index (coalesced: 16x16B=256B)
  const int np = t >> 4;             // n-pair 0..15
#pragma unroll
  for (int j = 0; j < 2; ++j) {
    const int npg = np + 16 * j;                       // 0..31
    const float* p0 = x + (size_t)(n0 + 2 * npg) * D_DIM + d0 + 4 * f4;
    float4 v0 = *(const float4*)p0;                    // row n even
    float4 v1 = *(const float4*)(p0 + D_DIM);          // row n odd
    unsigned int w0 = f2bf_u(v0.x) | (f2bf_u(v1.x) << 16);
    unsigned int w1 = f2bf_u(v0.y) | (f2bf_u(v1.y) << 16);
    unsigned int w2 = f2bf_u(v0.z) | (f2bf_u(v1.z) << 16);
    unsigned int w3 = f2bf_u(v0.w) | (f2bf_u(v1.w) << 16);
    tileT[(4 * f4 + 0) * 33 + npg] = w0;
    tileT[(4 * f4 + 1) * 33 + npg] = w1;
    tileT[(4 * f4 + 2) * 33 + npg] = w2;
    tileT[(4 * f4 + 3) * 33 + npg] = w3;
  }
  __syncthreads();
  const int ch = t & 7;              // 4-dword chunk along n (8 bf16)
  const int dr = t >> 3;             // 0..31
#pragma unroll
  for (int j = 0; j < 2; ++j) {
    const int dd = dr + 32 * j;
    const unsigned int* row = &tileT[dd * 33 + ch * 4];  // dword-aligned reads
    uint4 o; o.x = row[0]; o.y = row[1]; o.z = row[2]; o.w = row[3];
    *(uint4*)(xt + (size_t)(d0 + dd) * K_DIM + n0 + ch * 8) = o;
  }
}

// ---------------- K2: Gram GEMM, upper tile-pairs --------------------------
template<int KS, bool ATOMIC>
__global__ __launch_bounds__(256, 4) void gram_gemm_kernel(
    const unsigned short* __restrict__ xt,
    unsigned short* __restrict__ partials,   // bf16 [KS][NPAIR][16384]
    float* __restrict__ out) {
  __shared__ __align__(16) unsigned short ldsA[128 * 32];
  __shared__ __align__(16) unsigned short ldsB[128 * 32];

  const int p  = blockIdx.x;
  const int mi = MI_TAB[p];
  const int ni = NI_TAB[p];
  const int m0 = mi * 128;
  const int n0 = ni * 128;
  const int kz = blockIdx.y;

  const int t    = threadIdx.x;
  const int wave = t >> 6;
  const int lane = t & 63;
  const int wm   = (wave >> 1) * 64;
  const int wn   = (wave & 1) * 64;
  const int lm   = lane & 15;
  const int quad = lane >> 4;

  floatx4 zero = {0.f, 0.f, 0.f, 0.f};
  floatx4 acc[4][4];
#pragma unroll
  for (int a = 0; a < 4; ++a)
#pragma unroll
    for (int b = 0; b < 4; ++b) acc[a][b] = zero;

  const int kbeg = kz * (K_DIM / KS);

  for (int it = 0; it < (K_DIM / KS) / 32; ++it) {
    const int kb = kbeg + it * 32;
#pragma unroll
    for (int i = 0; i < 2; ++i) {
      const int c     = wave * 2 + i;
      const int flatL = c * 64 + lane;
      const int rrow  = flatL >> 2;
      const int sub   = flatL & 3;
      const unsigned short* gA = xt + (size_t)(m0 + rrow) * K_DIM + kb + sub * 8;
      const unsigned short* gB = xt + (size_t)(n0 + rrow) * K_DIM + kb + sub * 8;
      load_lds16(gA, &ldsA[flatL * 8]);
      load_lds16(gB, &ldsB[flatL * 8]);
    }
    __syncthreads();

    short8 af[4], bf[4];
#pragma unroll
    for (int a = 0; a < 4; ++a)
      af[a] = *(const short8*)&ldsA[(wm + a * 16 + lm) * 32 + quad * 8];
#pragma unroll
    for (int b = 0; b < 4; ++b)
      bf[b] = *(const short8*)&ldsB[(wn + b * 16 + lm) * 32 + quad * 8];

#pragma unroll
    for (int a = 0; a < 4; ++a)
#pragma unroll
      for (int b = 0; b < 4; ++b)
        acc[a][b] = __builtin_amdgcn_mfma_f32_16x16x32_bf16(
            af[a], bf[b], acc[a][b], 0, 0, 0);

    __syncthreads();
  }

  if (ATOMIC) {
    const float scale = 0.5f / (float)K_DIM;
#pragma unroll
    for (int a = 0; a < 4; ++a)
#pragma unroll
      for (int b = 0; b < 4; ++b)
#pragma unroll
        for (int r2 = 0; r2 < 4; ++r2) {
          const int grow = m0 + wm + a * 16 + quad * 4 + r2;
          const int gcol = n0 + wn + b * 16 + lm;
          atomicAdd(&out[(size_t)grow * D_DIM + gcol], acc[a][b][r2] * scale);
        }
  } else {
    unsigned short* pb = partials + ((size_t)kz * NPAIR + p) * 16384;
#pragma unroll
    for (int a = 0; a < 4; ++a)
#pragma unroll
      for (int b = 0; b < 4; ++b)
#pragma unroll
        for (int r2 = 0; r2 < 4; ++r2) {
          const int lr = wm + a * 16 + quad * 4 + r2;
          const int lc = wn + b * 16 + lm;
          pb[lr * 128 + lc] = (unsigned short)f2bf_u(acc[a][b][r2]);
        }
  }
}

// ---------------- K3: reduce + affine, upper tiles only --------------------
// thread handles 8 consecutive elems; uint4 loads of bf16 partials.
// grid: 21*2048/256 = 168 blocks.
__global__ __launch_bounds__(256) void reduce_kernel(
    const unsigned short* __restrict__ partials, float* __restrict__ out) {
  const int g  = blockIdx.x * 256 + threadIdx.x;
  const int p  = g >> 11;                 // pair (2048 groups-of-8 per tile)
  const int e0 = (g & 2047) * 8;          // elem base within 128x128 tile
  float s[8];
#pragma unroll
  for (int i = 0; i < 8; ++i) s[i] = 0.f;
#pragma unroll
  for (int kz = 0; kz < KSPLIT; ++kz) {
    const uint4 v = *(const uint4*)(partials + ((size_t)kz * NPAIR + p) * 16384 + e0);
    const unsigned int u[4] = {v.x, v.y, v.z, v.w};
#pragma unroll
    for (int i = 0; i < 4; ++i) {
      s[2 * i]     += __uint_as_float(u[i] << 16);          // low short
      s[2 * i + 1] += __uint_as_float(u[i] & 0xffff0000u);  // high short
    }
  }
  const float scale = 0.5f / (float)K_DIM;
  const int mi = MI_TAB[p], ni = NI_TAB[p];
  const int r = e0 >> 7, c = e0 & 127;
  float* o = out + (size_t)(mi * 128 + r) * D_DIM + ni * 128 + c;
  float4 lo, hi;
  lo.x = fmaf(s[0], scale, -0.5f); lo.y = fmaf(s[1], scale, -0.5f);
  lo.z = fmaf(s[2], scale, -0.5f); lo.w = fmaf(s[3], scale, -0.5f);
  hi.x = fmaf(s[4], scale, -0.5f); hi.y = fmaf(s[5], scale, -0.5f);
  hi.z = fmaf(s[6], scale, -0.5f); hi.w = fmaf(s[7], scale, -0.5f);
  *(float4*)o = lo;
  *(float4*)(o + 4) = hi;
}

// ---------------- K4: mirror off-diag tiles, LDS-transposed ----------------
// grid: 15 pairs * 4 sub-tiles (64x64) = 60 blocks.
__global__ __launch_bounds__(256) void mirror_kernel(float* __restrict__ out) {
  __shared__ __align__(16) float lt[64 * 65];   // [src_col][src_row], stride 65
  const int pr  = blockIdx.x >> 2;
  const int sub = blockIdx.x & 3;
  const int sr = sub >> 1, sc = sub & 1;
  const int mi = MI_OD[pr], ni = NI_OD[pr];
  const int SR0 = mi * 128 + sr * 64, SC0 = ni * 128 + sc * 64;  // src (upper)
  const int DR0 = ni * 128 + sc * 64, DC0 = mi * 128 + sr * 64;  // dst (lower)
  const int t  = threadIdx.x;
  const int f4 = t & 15;
  const int r  = t >> 4;
#pragma unroll
  for (int i = 0; i < 4; ++i) {
    const int row = r + 16 * i;
    float4 v = *(const float4*)(out + (size_t)(SR0 + row) * D_DIM + SC0 + 4 * f4);
    lt[(4 * f4 + 0) * 65 + row] = v.x;
    lt[(4 * f4 + 1) * 65 + row] = v.y;
    lt[(4 * f4 + 2) * 65 + row] = v.z;
    lt[(4 * f4 + 3) * 65 + row] = v.w;
  }
  __syncthreads();
#pragma unroll
  for (int i = 0; i < 4; ++i) {
    const int a = r + 16 * i;                  // dst row
    const float* lr = &lt[a * 65 + 4 * f4];    // dword reads (2-way banks)
    float4 o; o.x = lr[0]; o.y = lr[1]; o.z = lr[2]; o.w = lr[3];
    *(float4*)(out + (size_t)(DR0 + a) * D_DIM + DC0 + 4 * f4) = o;
  }
}

// ---------------- fallback (small ws): atomic path -------------------------
__global__ __launch_bounds__(256) void init_out_kernel(float* __restrict__ out) {
  size_t i = (size_t)blockIdx.x * 256 + threadIdx.x;
  ((float4*)out)[i] = make_float4(-0.5f, -0.5f, -0.5f, -0.5f);
}
__global__ __launch_bounds__(256) void mirror_full_kernel(float* __restrict__ out) {
  const int idx = blockIdx.x * 256 + threadIdx.x;
  const int r = idx / D_DIM;
  const int c = idx - r * D_DIM;
  if ((r >> 7) > (c >> 7))
    out[idx] = out[(size_t)c * D_DIM + r];
}

extern "C" void kernel_launch(void* const* d_in, const int* in_sizes, int n_in,
                              void* d_out, int out_size, void* d_ws, size_t ws_size,
                              hipStream_t stream) {
  const float* x = (const float*)d_in[0];           // [16384,768] f32
  float* out = (float*)d_out;                       // [768,768] f32
  unsigned short* xt = (unsigned short*)d_ws;       // bf16 [768][16384]

  transpose_cast_kernel<<<dim3(12, 256), 256, 0, stream>>>(x, xt);

  if (ws_size >= XT_BYTES + PART_BYTES) {
    unsigned short* parts = (unsigned short*)((char*)d_ws + XT_BYTES);
    gram_gemm_kernel<KSPLIT, false><<<dim3(NPAIR, KSPLIT), 256, 0, stream>>>(xt, parts, out);
    reduce_kernel<<<NPAIR * 2048 / 256, 256, 0, stream>>>(parts, out);
    mirror_kernel<<<60, 256, 0, stream>>>(out);
  } else {
    init_out_kernel<<<576, 256, 0, stream>>>(out);
    gram_gemm_kernel<8, true><<<dim3(NPAIR, 8), 256, 0, stream>>>(xt, nullptr, out);
    mirror_full_kernel<<<2304, 256, 0, stream>>>(out);
  }
}